// Round 4
// baseline (726.477 us; speedup 1.0000x reference)
//
#include <hip/hip_runtime.h>
#include <hip/hip_bf16.h>

// VQ-VAE vector quantizer, MI355X — round 4: bf16-MFMA screen + exact refine.
// Round-3 bug: swz_kernel grid covered only 16/64 tiles (codes 0..255); codes
// 256..1023 screened against 0xAA poison -> missed candidates. Fixed grid
// (<<<128,256>>> = 32768 threads = full 512 KB image) + MARGIN 1e-3 -> 3e-3
// (now dominates the adversarial 2E bound ~1.6e-3).
//
// Correctness: refinement recomputes keys bit-identically to round 2's passing
// scheme for every candidate within MARGIN of the approx row-min; candidate
// set provably contains the exact argmin; list overflow -> exact full scan.
//
// d_out (float32): [0..16777215] z_q_st, [16777216] vq_loss, [+1..] indices.
// d_ws: [0, 512K) cb_swz bf16 image; [512K, +4K) c2 fp32; [528384, +8K) partials f64.

constexpr int D     = 256;
constexpr int NC    = 1024;
constexpr int NROWS = 65536;
constexpr int RPB   = 64;        // rows per block
constexpr int ZS    = 264;       // z_lds stride (floats)
constexpr int CAP   = 16;        // candidate list capacity per row
#define MARGIN 3e-3f

typedef float accv4  __attribute__((ext_vector_type(4)));
typedef short short8 __attribute__((ext_vector_type(8)));

__device__ __forceinline__ short f2bf(float x) {
    __hip_bfloat16 h = __float2bfloat16(x);   // RNE
    return *reinterpret_cast<short*>(&h);
}

// numpy pairwise sum of x[0..127]^2 — 8-chain scheme (round-2 verified).
__device__ __forceinline__ float np_pairwise_sq128(const float* __restrict__ x) {
    float r[8];
    #pragma unroll
    for (int j = 0; j < 8; ++j) r[j] = __fmul_rn(x[j], x[j]);
    #pragma unroll
    for (int i = 8; i < 128; i += 8)
        #pragma unroll
        for (int j = 0; j < 8; ++j)
            r[j] = __fadd_rn(r[j], __fmul_rn(x[i + j], x[i + j]));
    float s01 = __fadd_rn(r[0], r[1]);
    float s23 = __fadd_rn(r[2], r[3]);
    float s45 = __fadd_rn(r[4], r[5]);
    float s67 = __fadd_rn(r[6], r[7]);
    return __fadd_rn(__fadd_rn(s01, s23), __fadd_rn(s45, s67));
}

// --- prep: per-code norms (round-2 identical) -------------------------------
__global__ void c2_kernel(const float* __restrict__ cb, float* __restrict__ c2) {
    int t = blockIdx.x * blockDim.x + threadIdx.x;
    if (t < NC) {
        const float* x = cb + (size_t)t * D;
        c2[t] = __fadd_rn(np_pairwise_sq128(x), np_pairwise_sq128(x + 128));
    }
}

// --- prep: swizzle codebook into MFMA B-fragment byte image -----------------
// short8 element t = tile*512 + ks*64 + lane holds
//   cb[tile*16 + (lane&15)][ks*32 + (lane>>4)*8 + j],  j=0..7
// Total: 64 tiles * 512 = 32768 short8 -> grid 128*256.
__global__ void swz_kernel(const float* __restrict__ cb, short* __restrict__ swz) {
    int t = blockIdx.x * blockDim.x + threadIdx.x;   // 0..32767
    int lane = t & 63, ts = t >> 6;
    int ks = ts & 7, tile = ts >> 3;
    int code = tile * 16 + (lane & 15);
    int kb   = ks * 32 + (lane >> 4) * 8;
    const float* src = cb + (size_t)code * D + kb;
    union { short s[8]; short8 v; } u;
    #pragma unroll
    for (int j = 0; j < 8; ++j) u.s[j] = f2bf(src[j]);
    *((short8*)swz + t) = u.v;
}

// --- main: screen + collect + refine + epilogue -----------------------------
__global__ __launch_bounds__(256, 2) void vq_kernel(
    const float* __restrict__ z,
    const float* __restrict__ cb,
    const short* __restrict__ cb_swz,
    const float* __restrict__ c2g,
    float*       __restrict__ out_zq,
    float*       __restrict__ out_idx,
    double*      __restrict__ partials)
{
    __shared__ __align__(16) float z_lds[RPB][ZS];     // 67584 B
    __shared__ float a_row[RPB];                        // 256 B
    __shared__ __align__(16) float scratchA[RPB][4];    // 1024 B (A_n tree; then best64)
    __shared__ float c2_lds[NC];                        // 4096 B
    __shared__ int   rm_shared[RPB];                    // 256 B (approx row min; then winners)
    __shared__ int   cnt[RPB];                          // 256 B
    __shared__ __align__(16) int lists[RPB][CAP];       // 4096 B (then f64 loss scratch)

    const int tid     = threadIdx.x;
    const int lane    = tid & 63;
    const int w       = tid >> 6;         // wave 0..3
    const int rowBase = blockIdx.x * RPB;

    // ---- phase 1: stage z, c2, init ----
    #pragma unroll
    for (int j = 0; j < 16; ++j) {
        int l = tid + 256 * j;
        int row = l >> 6, q = l & 63;
        float4 v = *(const float4*)(z + (size_t)(rowBase + row) * D + q * 4);
        *(float4*)&z_lds[row][q * 4] = v;
    }
    #pragma unroll
    for (int j = 0; j < 4; ++j) c2_lds[tid + 256 * j] = c2g[tid + 256 * j];
    if (tid < RPB) { rm_shared[tid] = 0x7f800000; cnt[tid] = 0; }
    __syncthreads();

    // ---- phase 2: A_n (numpy pairwise, exact round-2 tree), 4 threads/row ----
    {
        int row = tid >> 2, q = tid & 3;
        int h = (q >> 1) * 128, p = (q & 1) * 4;
        const float* x = &z_lds[row][0];
        float r0 = __fmul_rn(x[h+p+0], x[h+p+0]);
        float r1 = __fmul_rn(x[h+p+1], x[h+p+1]);
        float r2 = __fmul_rn(x[h+p+2], x[h+p+2]);
        float r3 = __fmul_rn(x[h+p+3], x[h+p+3]);
        #pragma unroll
        for (int i = 8; i < 128; i += 8) {
            r0 = __fadd_rn(r0, __fmul_rn(x[h+i+p+0], x[h+i+p+0]));
            r1 = __fadd_rn(r1, __fmul_rn(x[h+i+p+1], x[h+i+p+1]));
            r2 = __fadd_rn(r2, __fmul_rn(x[h+i+p+2], x[h+i+p+2]));
            r3 = __fadd_rn(r3, __fmul_rn(x[h+i+p+3], x[h+i+p+3]));
        }
        scratchA[row][q] = __fadd_rn(__fadd_rn(r0, r1), __fadd_rn(r2, r3));
    }
    __syncthreads();
    if (tid < RPB) {
        float half0 = __fadd_rn(scratchA[tid][0], scratchA[tid][1]);
        float half1 = __fadd_rn(scratchA[tid][2], scratchA[tid][3]);
        a_row[tid]  = __fadd_rn(half0, half1);
    }
    __syncthreads();

    // ---- phase 3: build register-resident A-fragments (bf16) ----
    short8 afrag[4][8];
    #pragma unroll
    for (int rt = 0; rt < 4; ++rt)
        #pragma unroll
        for (int ks = 0; ks < 8; ++ks) {
            const float* src = &z_lds[rt * 16 + (lane & 15)][ks * 32 + (lane >> 4) * 8];
            union { short s[8]; short8 v; } u;
            #pragma unroll
            for (int j = 0; j < 8; ++j) u.s[j] = f2bf(src[j]);
            afrag[rt][ks] = u.v;
        }
    float a_reg[4][4];
    #pragma unroll
    for (int rt = 0; rt < 4; ++rt)
        #pragma unroll
        for (int i = 0; i < 4; ++i)
            a_reg[rt][i] = a_row[rt * 16 + (lane >> 4) * 4 + i];

    float runmin[4][4];
    #pragma unroll
    for (int rt = 0; rt < 4; ++rt)
        #pragma unroll
        for (int i = 0; i < 4; ++i) runmin[rt][i] = 3.4e38f;

    // ---- phase 4: MFMA screen over this wave's 16 code-tiles (no barriers) ----
    for (int t = 0; t < 16; ++t) {
        int tile = w + 4 * t;
        const short8* bp = (const short8*)cb_swz + (size_t)tile * 512 + lane;
        accv4 acc[4];
        #pragma unroll
        for (int rt = 0; rt < 4; ++rt) acc[rt] = (accv4){0.f, 0.f, 0.f, 0.f};
        #pragma unroll
        for (int ks = 0; ks < 8; ++ks) {
            short8 b = bp[ks * 64];
            #pragma unroll
            for (int rt = 0; rt < 4; ++rt)
                acc[rt] = __builtin_amdgcn_mfma_f32_16x16x32_bf16(
                    afrag[rt][ks], b, acc[rt], 0, 0, 0);
        }
        int   col  = lane & 15;
        int   code = tile * 16 + col;
        float c2v  = c2_lds[code];
        #pragma unroll
        for (int rt = 0; rt < 4; ++rt)
            #pragma unroll
            for (int i = 0; i < 4; ++i) {
                int row = rt * 16 + (lane >> 4) * 4 + i;
                float key = (a_reg[rt][i] + c2v) - 2.0f * acc[rt][i];
                float m = key;
                m = fminf(m, __shfl_xor(m, 1));
                m = fminf(m, __shfl_xor(m, 2));
                m = fminf(m, __shfl_xor(m, 4));
                m = fminf(m, __shfl_xor(m, 8));
                runmin[rt][i] = fminf(runmin[rt][i], m);
                if (col == 0) atomicMin(&rm_shared[row], __float_as_int(m));
                float thr = fminf(runmin[rt][i],
                                  __int_as_float(rm_shared[row])) + MARGIN;
                if (key <= thr) {
                    int slot = atomicAdd(&cnt[row], 1);
                    if (slot < CAP) lists[row][slot] = code;
                }
            }
    }
    __syncthreads();

    // ---- phase 5: exact refinement (bit-identical to round-2 keys) ----
    unsigned long long* best64 = (unsigned long long*)&scratchA[0][0];
    if (tid < RPB) best64[tid] = ~0ull;
    __syncthreads();
    for (int r = 0; r < RPB; ++r) {
        int  cn  = cnt[r];
        bool ovf = cn > CAP;
        int  n   = ovf ? NC : cn;
        for (int c = tid; c < n; c += 256) {
            int code = ovf ? c : lists[r][c];
            const float4* cp = (const float4*)(cb + (size_t)code * D);
            const float*  zr = &z_lds[r][0];
            float acc = 0.0f;
            #pragma unroll 8
            for (int d4 = 0; d4 < 64; ++d4) {
                float4 cv = cp[d4];
                acc = fmaf(zr[d4 * 4 + 0], cv.x, acc);
                acc = fmaf(zr[d4 * 4 + 1], cv.y, acc);
                acc = fmaf(zr[d4 * 4 + 2], cv.z, acc);
                acc = fmaf(zr[d4 * 4 + 3], cv.w, acc);
            }
            float key = __fsub_rn(__fadd_rn(a_row[r], c2_lds[code]), 2.0f * acc);
            unsigned long long pk =
                ((unsigned long long)__float_as_uint(key) << 32) | (unsigned)code;
            atomicMin(&best64[r], pk);
        }
    }
    __syncthreads();

    // ---- phase 6: winners ----
    int* winner = rm_shared;   // reuse
    if (tid < RPB) {
        int wdx = (int)(best64[tid] & 0xffffffffu);
        winner[tid] = wdx;
        out_idx[rowBase + tid] = (float)wdx;
    }
    __syncthreads();

    // ---- phase 7: z_q_st + loss (round-2 identical epilogue) ----
    double lacc = 0.0;
    for (int r = 0; r < RPB; ++r) {
        int   wd = winner[r];
        float q  = cb[(size_t)wd * D + tid];
        float ze = z_lds[r][tid];
        out_zq[(size_t)(rowBase + r) * D + tid] = __fadd_rn(ze, __fsub_rn(q, ze));
        double dd = (double)ze - (double)q;
        lacc += dd * dd;
    }
    __syncthreads();
    double* dred = (double*)&lists[0][0];
    dred[tid] = lacc;
    __syncthreads();
    for (int s = 128; s > 0; s >>= 1) {
        if (tid < s) dred[tid] += dred[tid + s];
        __syncthreads();
    }
    if (tid == 0) partials[blockIdx.x] = dred[0];
}

// --- final loss reduction ---------------------------------------------------
__global__ void loss_kernel(const double* __restrict__ partials,
                            float* __restrict__ out_loss)
{
    __shared__ double sm[256];
    int tid = threadIdx.x;
    double s = 0.0;
    for (int i = tid; i < NROWS / RPB; i += 256) s += partials[i];
    sm[tid] = s;
    __syncthreads();
    for (int k = 128; k > 0; k >>= 1) {
        if (tid < k) sm[tid] += sm[tid + k];
        __syncthreads();
    }
    if (tid == 0)
        out_loss[0] = (float)(1.25 * sm[0] / (double)((size_t)NROWS * D));
}

extern "C" void kernel_launch(void* const* d_in, const int* in_sizes, int n_in,
                              void* d_out, int out_size, void* d_ws, size_t ws_size,
                              hipStream_t stream)
{
    const float* z  = (const float*)d_in[0];   // [65536, 256]
    const float* cb = (const float*)d_in[1];   // [1024, 256]

    float* out      = (float*)d_out;
    float* out_zq   = out;
    float* out_loss = out + (size_t)NROWS * D;
    float* out_idx  = out_loss + 1;

    char*   ws       = (char*)d_ws;
    short*  cb_swz   = (short*)ws;                       // 512 KB
    float*  c2       = (float*)(ws + 524288);            // 4 KB
    double* partials = (double*)(ws + 528384);           // 8 KB

    swz_kernel<<<128, 256, 0, stream>>>(cb, cb_swz);     // 32768 short8 = full image
    c2_kernel<<<4, 256, 0, stream>>>(cb, c2);
    vq_kernel<<<NROWS / RPB, 256, 0, stream>>>(z, cb, cb_swz, c2,
                                               out_zq, out_idx, partials);
    loss_kernel<<<1, 256, 0, stream>>>(partials, out_loss);
}

// Round 5
// 366.100 us; speedup vs baseline: 1.9844x; 1.9844x over previous
//
#include <hip/hip_runtime.h>
#include <hip/hip_bf16.h>

// VQ-VAE vector quantizer, MI355X — round 5: TWO-PASS bf16-MFMA screen.
// Round-4 failure mode: collection against a cold per-wave running min
// over-collected (~14/row across 4 waves) -> CAP overflow -> full exact scan
// per row (= round-2 workload, 650 us). Fix: pass 1 computes the true approx
// row-min (register fminf + one shfl tree + one atomicMin), pass 2 recomputes
// the identical MFMA keys and collects only key <= rowmin + MARGIN into one
// flat block queue (~1.3 candidates/row). Refinement is bit-identical to the
// round-2-verified fp32 arithmetic, so indices are provably unchanged.
//
// d_out (float32): [0..16777215] z_q_st, [16777216] vq_loss, [+1..] indices.
// d_ws: [0,512K) cb_swz bf16 image; [512K,+4K) c2 fp32; [528384,+8K) partials.

constexpr int D     = 256;
constexpr int NC    = 1024;
constexpr int NROWS = 65536;
constexpr int RPB   = 64;        // rows per block
constexpr int ZS    = 264;       // z_lds stride (floats)
constexpr int QCAP  = 1024;      // block-wide candidate queue capacity
#define MARGIN 3e-3f

typedef float accv4  __attribute__((ext_vector_type(4)));
typedef short short8 __attribute__((ext_vector_type(8)));

__device__ __forceinline__ short f2bf(float x) {
    __hip_bfloat16 h = __float2bfloat16(x);   // RNE
    return *reinterpret_cast<short*>(&h);
}

// numpy pairwise sum of x[0..127]^2 — 8-chain scheme (round-2 verified).
__device__ __forceinline__ float np_pairwise_sq128(const float* __restrict__ x) {
    float r[8];
    #pragma unroll
    for (int j = 0; j < 8; ++j) r[j] = __fmul_rn(x[j], x[j]);
    #pragma unroll
    for (int i = 8; i < 128; i += 8)
        #pragma unroll
        for (int j = 0; j < 8; ++j)
            r[j] = __fadd_rn(r[j], __fmul_rn(x[i + j], x[i + j]));
    float s01 = __fadd_rn(r[0], r[1]);
    float s23 = __fadd_rn(r[2], r[3]);
    float s45 = __fadd_rn(r[4], r[5]);
    float s67 = __fadd_rn(r[6], r[7]);
    return __fadd_rn(__fadd_rn(s01, s23), __fadd_rn(s45, s67));
}

// --- prep: per-code norms (round-2 identical) -------------------------------
__global__ void c2_kernel(const float* __restrict__ cb, float* __restrict__ c2) {
    int t = blockIdx.x * blockDim.x + threadIdx.x;
    if (t < NC) {
        const float* x = cb + (size_t)t * D;
        c2[t] = __fadd_rn(np_pairwise_sq128(x), np_pairwise_sq128(x + 128));
    }
}

// --- prep: swizzle codebook into MFMA B-fragment byte image -----------------
// short8 element t = tile*512 + ks*64 + lane holds
//   cb[tile*16 + (lane&15)][ks*32 + (lane>>4)*8 + j],  j=0..7
__global__ void swz_kernel(const float* __restrict__ cb, short* __restrict__ swz) {
    int t = blockIdx.x * blockDim.x + threadIdx.x;   // 0..32767
    int lane = t & 63, ts = t >> 6;
    int ks = ts & 7, tile = ts >> 3;
    int code = tile * 16 + (lane & 15);
    int kb   = ks * 32 + (lane >> 4) * 8;
    const float* src = cb + (size_t)code * D + kb;
    union { short s[8]; short8 v; } u;
    #pragma unroll
    for (int j = 0; j < 8; ++j) u.s[j] = f2bf(src[j]);
    *((short8*)swz + t) = u.v;
}

// --- main: 2-pass screen + flat refine + epilogue ---------------------------
__global__ __launch_bounds__(256, 2) void vq_kernel(
    const float* __restrict__ z,
    const float* __restrict__ cb,
    const short* __restrict__ cb_swz,
    const float* __restrict__ c2g,
    float*       __restrict__ out_zq,
    float*       __restrict__ out_idx,
    double*      __restrict__ partials)
{
    __shared__ __align__(16) float z_lds[RPB][ZS];     // 67584 B
    __shared__ float a_row[RPB];                        // 256 B
    __shared__ __align__(16) float scratchA[RPB][4];    // 1024 B (A_n tree; then best64)
    __shared__ float c2_lds[NC];                        // 4096 B
    __shared__ int   rm_shared[RPB];                    // 256 B (approx min; then winners)
    __shared__ __align__(16) int queue[QCAP];           // 4096 B (then f64 loss scratch)
    __shared__ int   qn;

    const int tid     = threadIdx.x;
    const int lane    = tid & 63;
    const int w       = tid >> 6;         // wave 0..3
    const int rowBase = blockIdx.x * RPB;

    // ---- phase 1: stage z, c2, init ----
    #pragma unroll
    for (int j = 0; j < 16; ++j) {
        int l = tid + 256 * j;
        int row = l >> 6, q = l & 63;
        float4 v = *(const float4*)(z + (size_t)(rowBase + row) * D + q * 4);
        *(float4*)&z_lds[row][q * 4] = v;
    }
    #pragma unroll
    for (int j = 0; j < 4; ++j) c2_lds[tid + 256 * j] = c2g[tid + 256 * j];
    if (tid < RPB) rm_shared[tid] = 0x7f800000;   // +inf
    if (tid == 0)  qn = 0;
    __syncthreads();

    // ---- phase 2: A_n (numpy pairwise, round-2-exact tree), 4 threads/row ----
    {
        int row = tid >> 2, q = tid & 3;
        int h = (q >> 1) * 128, p = (q & 1) * 4;
        const float* x = &z_lds[row][0];
        float r0 = __fmul_rn(x[h+p+0], x[h+p+0]);
        float r1 = __fmul_rn(x[h+p+1], x[h+p+1]);
        float r2 = __fmul_rn(x[h+p+2], x[h+p+2]);
        float r3 = __fmul_rn(x[h+p+3], x[h+p+3]);
        #pragma unroll
        for (int i = 8; i < 128; i += 8) {
            r0 = __fadd_rn(r0, __fmul_rn(x[h+i+p+0], x[h+i+p+0]));
            r1 = __fadd_rn(r1, __fmul_rn(x[h+i+p+1], x[h+i+p+1]));
            r2 = __fadd_rn(r2, __fmul_rn(x[h+i+p+2], x[h+i+p+2]));
            r3 = __fadd_rn(r3, __fmul_rn(x[h+i+p+3], x[h+i+p+3]));
        }
        scratchA[row][q] = __fadd_rn(__fadd_rn(r0, r1), __fadd_rn(r2, r3));
    }
    __syncthreads();
    if (tid < RPB) {
        float half0 = __fadd_rn(scratchA[tid][0], scratchA[tid][1]);
        float half1 = __fadd_rn(scratchA[tid][2], scratchA[tid][3]);
        a_row[tid]  = __fadd_rn(half0, half1);
    }
    __syncthreads();

    // ---- phase 3: register-resident bf16 A-fragments ----
    short8 afrag[4][8];
    #pragma unroll
    for (int rt = 0; rt < 4; ++rt)
        #pragma unroll
        for (int ks = 0; ks < 8; ++ks) {
            const float* src = &z_lds[rt * 16 + (lane & 15)][ks * 32 + (lane >> 4) * 8];
            union { short s[8]; short8 v; } u;
            #pragma unroll
            for (int j = 0; j < 8; ++j) u.s[j] = f2bf(src[j]);
            afrag[rt][ks] = u.v;
        }
    float a_reg[4][4];
    #pragma unroll
    for (int rt = 0; rt < 4; ++rt)
        #pragma unroll
        for (int i = 0; i < 4; ++i)
            a_reg[rt][i] = a_row[rt * 16 + (lane >> 4) * 4 + i];

    float runmin[4][4], thr[4][4];
    #pragma unroll
    for (int rt = 0; rt < 4; ++rt)
        #pragma unroll
        for (int i = 0; i < 4; ++i) runmin[rt][i] = 3.4e38f;

    // ---- phase 4: two-pass MFMA screen ----
    for (int pass = 0; pass < 2; ++pass) {
        for (int t = 0; t < 16; ++t) {
            int tile = w + 4 * t;
            const short8* bp = (const short8*)cb_swz + (size_t)tile * 512 + lane;
            accv4 acc[4];
            #pragma unroll
            for (int rt = 0; rt < 4; ++rt) acc[rt] = (accv4){0.f, 0.f, 0.f, 0.f};
            #pragma unroll
            for (int ks = 0; ks < 8; ++ks) {
                short8 b = bp[ks * 64];
                #pragma unroll
                for (int rt = 0; rt < 4; ++rt)
                    acc[rt] = __builtin_amdgcn_mfma_f32_16x16x32_bf16(
                        afrag[rt][ks], b, acc[rt], 0, 0, 0);
            }
            int   col  = lane & 15;
            int   code = tile * 16 + col;
            float c2v  = c2_lds[code];
            #pragma unroll
            for (int rt = 0; rt < 4; ++rt)
                #pragma unroll
                for (int i = 0; i < 4; ++i) {
                    float key = (a_reg[rt][i] + c2v) - 2.0f * acc[rt][i];
                    if (pass == 0) {
                        runmin[rt][i] = fminf(runmin[rt][i], key);
                    } else if (key <= thr[rt][i]) {
                        int row  = rt * 16 + (lane >> 4) * 4 + i;
                        int slot = atomicAdd(&qn, 1);
                        if (slot < QCAP) queue[slot] = (row << 10) | code;
                    }
                }
        }
        if (pass == 0) {
            // fold per-lane minima across the 16 columns, publish per-row min
            #pragma unroll
            for (int rt = 0; rt < 4; ++rt)
                #pragma unroll
                for (int i = 0; i < 4; ++i) {
                    float m = runmin[rt][i];
                    m = fminf(m, __shfl_xor(m, 1));
                    m = fminf(m, __shfl_xor(m, 2));
                    m = fminf(m, __shfl_xor(m, 4));
                    m = fminf(m, __shfl_xor(m, 8));
                    if ((lane & 15) == 0) {
                        int row = rt * 16 + (lane >> 4) * 4 + i;
                        atomicMin(&rm_shared[row], __float_as_int(m));
                    }
                }
            __syncthreads();
            #pragma unroll
            for (int rt = 0; rt < 4; ++rt)
                #pragma unroll
                for (int i = 0; i < 4; ++i) {
                    int row = rt * 16 + (lane >> 4) * 4 + i;
                    thr[rt][i] = __int_as_float(rm_shared[row]) + MARGIN;
                }
        }
    }

    // ---- phase 5: exact refinement (bit-identical to round-2 keys) ----
    unsigned long long* best64 = (unsigned long long*)&scratchA[0][0];
    if (tid < RPB) best64[tid] = ~0ull;
    __syncthreads();
    int total = qn;
    if (total <= QCAP) {
        for (int t = tid; t < total; t += 256) {
            int e = queue[t];
            int row = e >> 10, code = e & 1023;
            const float4* cp = (const float4*)(cb + (size_t)code * D);
            const float*  zr = &z_lds[row][0];
            float acc = 0.0f;
            #pragma unroll 8
            for (int d4 = 0; d4 < 64; ++d4) {
                float4 cv = cp[d4];
                acc = fmaf(zr[d4 * 4 + 0], cv.x, acc);
                acc = fmaf(zr[d4 * 4 + 1], cv.y, acc);
                acc = fmaf(zr[d4 * 4 + 2], cv.z, acc);
                acc = fmaf(zr[d4 * 4 + 3], cv.w, acc);
            }
            float key = __fsub_rn(__fadd_rn(a_row[row], c2_lds[code]), 2.0f * acc);
            unsigned long long pk =
                ((unsigned long long)__float_as_uint(key) << 32) | (unsigned)code;
            atomicMin(&best64[row], pk);
        }
    } else {
        // queue overflow (should never happen): exact full scan, all rows
        for (int r = 0; r < RPB; ++r) {
            for (int c = tid; c < NC; c += 256) {
                const float4* cp = (const float4*)(cb + (size_t)c * D);
                const float*  zr = &z_lds[r][0];
                float acc = 0.0f;
                #pragma unroll 8
                for (int d4 = 0; d4 < 64; ++d4) {
                    float4 cv = cp[d4];
                    acc = fmaf(zr[d4 * 4 + 0], cv.x, acc);
                    acc = fmaf(zr[d4 * 4 + 1], cv.y, acc);
                    acc = fmaf(zr[d4 * 4 + 2], cv.z, acc);
                    acc = fmaf(zr[d4 * 4 + 3], cv.w, acc);
                }
                float key = __fsub_rn(__fadd_rn(a_row[r], c2_lds[c]), 2.0f * acc);
                unsigned long long pk =
                    ((unsigned long long)__float_as_uint(key) << 32) | (unsigned)c;
                atomicMin(&best64[r], pk);
            }
        }
    }
    __syncthreads();

    // ---- phase 6: winners ----
    int* winner = rm_shared;   // reuse
    if (tid < RPB) {
        unsigned long long b = best64[tid];
        int wdx = (b == ~0ull) ? 0 : (int)(b & 0xffffffffu);
        winner[tid] = wdx;
        out_idx[rowBase + tid] = (float)wdx;
    }
    __syncthreads();

    // ---- phase 7: z_q_st + loss (round-2 identical epilogue) ----
    double lacc = 0.0;
    for (int r = 0; r < RPB; ++r) {
        int   wd = winner[r];
        float q  = cb[(size_t)wd * D + tid];
        float ze = z_lds[r][tid];
        out_zq[(size_t)(rowBase + r) * D + tid] = __fadd_rn(ze, __fsub_rn(q, ze));
        double dd = (double)ze - (double)q;
        lacc += dd * dd;
    }
    __syncthreads();
    double* dred = (double*)&queue[0];   // 2048 B of the 4096 B queue
    dred[tid] = lacc;
    __syncthreads();
    for (int s = 128; s > 0; s >>= 1) {
        if (tid < s) dred[tid] += dred[tid + s];
        __syncthreads();
    }
    if (tid == 0) partials[blockIdx.x] = dred[0];
}

// --- final loss reduction ---------------------------------------------------
__global__ void loss_kernel(const double* __restrict__ partials,
                            float* __restrict__ out_loss)
{
    __shared__ double sm[256];
    int tid = threadIdx.x;
    double s = 0.0;
    for (int i = tid; i < NROWS / RPB; i += 256) s += partials[i];
    sm[tid] = s;
    __syncthreads();
    for (int k = 128; k > 0; k >>= 1) {
        if (tid < k) sm[tid] += sm[tid + k];
        __syncthreads();
    }
    if (tid == 0)
        out_loss[0] = (float)(1.25 * sm[0] / (double)((size_t)NROWS * D));
}

extern "C" void kernel_launch(void* const* d_in, const int* in_sizes, int n_in,
                              void* d_out, int out_size, void* d_ws, size_t ws_size,
                              hipStream_t stream)
{
    const float* z  = (const float*)d_in[0];   // [65536, 256]
    const float* cb = (const float*)d_in[1];   // [1024, 256]

    float* out      = (float*)d_out;
    float* out_zq   = out;
    float* out_loss = out + (size_t)NROWS * D;
    float* out_idx  = out_loss + 1;

    char*   ws       = (char*)d_ws;
    short*  cb_swz   = (short*)ws;                       // 512 KB
    float*  c2       = (float*)(ws + 524288);            // 4 KB
    double* partials = (double*)(ws + 528384);           // 8 KB

    swz_kernel<<<128, 256, 0, stream>>>(cb, cb_swz);     // full 32768-short8 image
    c2_kernel<<<4, 256, 0, stream>>>(cb, c2);
    vq_kernel<<<NROWS / RPB, 256, 0, stream>>>(z, cb, cb_swz, c2,
                                               out_zq, out_idx, partials);
    loss_kernel<<<1, 256, 0, stream>>>(partials, out_loss);
}

// Round 6
// 256.107 us; speedup vs baseline: 2.8366x; 1.4295x over previous
//
#include <hip/hip_runtime.h>
#include <hip/hip_bf16.h>

// VQ-VAE vector quantizer, MI355X — round 6.
// Round-5 diagnosis: VGPR_Count=128 < afrag size (128 dwords) -> compiler
// rematerialized A-fragments per tile-step from LDS with 16-way bank
// conflicts + cvt chains (matches idle pipes + 1.17e7 LDS conflicts).
// Fixes: RPB 32 (afrag 64 dwords, plausibly resident), fragments built from
// global z via truncation-pack (no LDS, no cvt), B prefetch, vectorized
// epilogue. Refine arithmetic bit-identical to round-2 (verified) scheme.
//
// d_out (float32): [0..16777215] z_q_st, [16777216] vq_loss, [+1..] indices.
// d_ws: [0,512K) cb_swz; [512K,+4K) c2; [528384,+16K) partials f64.

constexpr int D     = 256;
constexpr int NC    = 1024;
constexpr int NROWS = 65536;
constexpr int RPB   = 32;        // rows per block
constexpr int NBLK  = NROWS / RPB;   // 2048
constexpr int ZS    = 264;       // z_lds stride (floats)
constexpr int QCAP  = 512;       // block-wide candidate queue capacity
#define MARGIN 3e-3f

typedef float accv4  __attribute__((ext_vector_type(4)));
typedef short short8 __attribute__((ext_vector_type(8)));

__device__ __forceinline__ short f2bf(float x) {
    __hip_bfloat16 h = __float2bfloat16(x);   // RNE (prep kernel only)
    return *reinterpret_cast<short*>(&h);
}
// pack truncated bf16(x) into low16, bf16(y) into high16 (2 VALU ops)
__device__ __forceinline__ unsigned packtrunc(float x, float y) {
    return (__float_as_uint(x) >> 16) | (__float_as_uint(y) & 0xffff0000u);
}

// numpy pairwise sum of x[0..127]^2 — 8-chain scheme (round-2 verified).
__device__ __forceinline__ float np_pairwise_sq128(const float* __restrict__ x) {
    float r[8];
    #pragma unroll
    for (int j = 0; j < 8; ++j) r[j] = __fmul_rn(x[j], x[j]);
    #pragma unroll
    for (int i = 8; i < 128; i += 8)
        #pragma unroll
        for (int j = 0; j < 8; ++j)
            r[j] = __fadd_rn(r[j], __fmul_rn(x[i + j], x[i + j]));
    float s01 = __fadd_rn(r[0], r[1]);
    float s23 = __fadd_rn(r[2], r[3]);
    float s45 = __fadd_rn(r[4], r[5]);
    float s67 = __fadd_rn(r[6], r[7]);
    return __fadd_rn(__fadd_rn(s01, s23), __fadd_rn(s45, s67));
}

// --- prep: per-code norms (round-2 identical) -------------------------------
__global__ void c2_kernel(const float* __restrict__ cb, float* __restrict__ c2) {
    int t = blockIdx.x * blockDim.x + threadIdx.x;
    if (t < NC) {
        const float* x = cb + (size_t)t * D;
        c2[t] = __fadd_rn(np_pairwise_sq128(x), np_pairwise_sq128(x + 128));
    }
}

// --- prep: swizzle codebook into MFMA B-fragment byte image -----------------
// short8 element t = tile*512 + ks*64 + lane holds
//   cb[tile*16 + (lane&15)][ks*32 + (lane>>4)*8 + j],  j=0..7
__global__ void swz_kernel(const float* __restrict__ cb, short* __restrict__ swz) {
    int t = blockIdx.x * blockDim.x + threadIdx.x;   // 0..32767
    int lane = t & 63, ts = t >> 6;
    int ks = ts & 7, tile = ts >> 3;
    int code = tile * 16 + (lane & 15);
    int kb   = ks * 32 + (lane >> 4) * 8;
    const float* src = cb + (size_t)code * D + kb;
    union { short s[8]; short8 v; } u;
    #pragma unroll
    for (int j = 0; j < 8; ++j) u.s[j] = f2bf(src[j]);
    *((short8*)swz + t) = u.v;
}

// --- main: 2-pass screen + flat refine + epilogue ---------------------------
__global__ __launch_bounds__(256, 2) void vq_kernel(
    const float* __restrict__ z,
    const float* __restrict__ cb,
    const short* __restrict__ cb_swz,
    const float* __restrict__ c2g,
    float*       __restrict__ out_zq,
    float*       __restrict__ out_idx,
    double*      __restrict__ partials)
{
    __shared__ __align__(16) float z_lds[RPB][ZS];     // 33792 B
    __shared__ float a_row[RPB];
    __shared__ __align__(16) float scratchA[RPB][4];   // A_n tree; then best64
    __shared__ float c2_lds[NC];                        // 4096 B
    __shared__ int   rm_shared[RPB];                    // approx min; then winners
    __shared__ __align__(16) int queue[QCAP];           // 2048 B; then f64 scratch
    __shared__ int   qn;

    const int tid     = threadIdx.x;
    const int lane    = tid & 63;
    const int w       = tid >> 6;         // wave 0..3
    const int rowBase = blockIdx.x * RPB;

    // ---- phase 1: stage z (fp32), c2, init ----
    #pragma unroll
    for (int j = 0; j < 8; ++j) {
        int l = tid + 256 * j;
        int row = l >> 6, q = l & 63;
        float4 v = *(const float4*)(z + (size_t)(rowBase + row) * D + q * 4);
        *(float4*)&z_lds[row][q * 4] = v;
    }
    #pragma unroll
    for (int j = 0; j < 4; ++j) c2_lds[tid + 256 * j] = c2g[tid + 256 * j];
    if (tid < RPB) rm_shared[tid] = 0x7f800000;   // +inf
    if (tid == 0)  qn = 0;
    __syncthreads();

    // ---- phase 2: A_n (numpy pairwise, round-2-exact tree), 4 threads/row ----
    if (tid < RPB * 4) {
        int row = tid >> 2, q = tid & 3;
        int h = (q >> 1) * 128, p = (q & 1) * 4;
        const float* x = &z_lds[row][0];
        float r0 = __fmul_rn(x[h+p+0], x[h+p+0]);
        float r1 = __fmul_rn(x[h+p+1], x[h+p+1]);
        float r2 = __fmul_rn(x[h+p+2], x[h+p+2]);
        float r3 = __fmul_rn(x[h+p+3], x[h+p+3]);
        #pragma unroll
        for (int i = 8; i < 128; i += 8) {
            r0 = __fadd_rn(r0, __fmul_rn(x[h+i+p+0], x[h+i+p+0]));
            r1 = __fadd_rn(r1, __fmul_rn(x[h+i+p+1], x[h+i+p+1]));
            r2 = __fadd_rn(r2, __fmul_rn(x[h+i+p+2], x[h+i+p+2]));
            r3 = __fadd_rn(r3, __fmul_rn(x[h+i+p+3], x[h+i+p+3]));
        }
        scratchA[row][q] = __fadd_rn(__fadd_rn(r0, r1), __fadd_rn(r2, r3));
    }
    __syncthreads();
    if (tid < RPB) {
        float half0 = __fadd_rn(scratchA[tid][0], scratchA[tid][1]);
        float half1 = __fadd_rn(scratchA[tid][2], scratchA[tid][3]);
        a_row[tid]  = __fadd_rn(half0, half1);
    }
    __syncthreads();

    // ---- phase 3: A-fragments from GLOBAL z (truncated bf16, no LDS) ----
    // lane L, row-tile rt, k-slice ks: rows rt*16+(L&15), dims ks*32+(L>>4)*8..+7
    short8 afrag[2][8];
    #pragma unroll
    for (int rt = 0; rt < 2; ++rt)
        #pragma unroll
        for (int ks = 0; ks < 8; ++ks) {
            const float* src = z + (size_t)(rowBase + rt * 16 + (lane & 15)) * D
                                 + ks * 32 + (lane >> 4) * 8;
            float4 v0 = *(const float4*)(src);
            float4 v1 = *(const float4*)(src + 4);
            union { unsigned u[4]; short8 v; } pk;
            pk.u[0] = packtrunc(v0.x, v0.y);
            pk.u[1] = packtrunc(v0.z, v0.w);
            pk.u[2] = packtrunc(v1.x, v1.y);
            pk.u[3] = packtrunc(v1.z, v1.w);
            afrag[rt][ks] = pk.v;
        }
    float a_reg[2][4];
    #pragma unroll
    for (int rt = 0; rt < 2; ++rt)
        #pragma unroll
        for (int i = 0; i < 4; ++i)
            a_reg[rt][i] = a_row[rt * 16 + (lane >> 4) * 4 + i];

    float runmin[2][4], thr[2][4];
    #pragma unroll
    for (int rt = 0; rt < 2; ++rt)
        #pragma unroll
        for (int i = 0; i < 4; ++i) runmin[rt][i] = 3.4e38f;

    // ---- phase 4: two-pass MFMA screen with B prefetch ----
    const short8* bbase = (const short8*)cb_swz + lane;
    for (int pass = 0; pass < 2; ++pass) {
        short8 bcur[8];
        #pragma unroll
        for (int ks = 0; ks < 8; ++ks) bcur[ks] = bbase[(size_t)w * 512 + ks * 64];
        for (int t = 0; t < 16; ++t) {
            int tile = w + 4 * t;
            short8 bnxt[8];
            if (t < 15) {
                int ntile = tile + 4;
                #pragma unroll
                for (int ks = 0; ks < 8; ++ks)
                    bnxt[ks] = bbase[(size_t)ntile * 512 + ks * 64];
            }
            accv4 acc[2];
            #pragma unroll
            for (int rt = 0; rt < 2; ++rt) acc[rt] = (accv4){0.f, 0.f, 0.f, 0.f};
            #pragma unroll
            for (int ks = 0; ks < 8; ++ks) {
                #pragma unroll
                for (int rt = 0; rt < 2; ++rt)
                    acc[rt] = __builtin_amdgcn_mfma_f32_16x16x32_bf16(
                        afrag[rt][ks], bcur[ks], acc[rt], 0, 0, 0);
            }
            int   col  = lane & 15;
            int   code = tile * 16 + col;
            float c2v  = c2_lds[code];
            #pragma unroll
            for (int rt = 0; rt < 2; ++rt)
                #pragma unroll
                for (int i = 0; i < 4; ++i) {
                    float key = (a_reg[rt][i] + c2v) - 2.0f * acc[rt][i];
                    if (pass == 0) {
                        runmin[rt][i] = fminf(runmin[rt][i], key);
                    } else if (key <= thr[rt][i]) {
                        int row  = rt * 16 + (lane >> 4) * 4 + i;
                        int slot = atomicAdd(&qn, 1);
                        if (slot < QCAP) queue[slot] = (row << 10) | code;
                    }
                }
            #pragma unroll
            for (int ks = 0; ks < 8; ++ks) bcur[ks] = bnxt[ks];
        }
        if (pass == 0) {
            #pragma unroll
            for (int rt = 0; rt < 2; ++rt)
                #pragma unroll
                for (int i = 0; i < 4; ++i) {
                    float m = runmin[rt][i];
                    m = fminf(m, __shfl_xor(m, 1));
                    m = fminf(m, __shfl_xor(m, 2));
                    m = fminf(m, __shfl_xor(m, 4));
                    m = fminf(m, __shfl_xor(m, 8));
                    if ((lane & 15) == 0) {
                        int row = rt * 16 + (lane >> 4) * 4 + i;
                        atomicMin(&rm_shared[row], __float_as_int(m));
                    }
                }
            __syncthreads();
            #pragma unroll
            for (int rt = 0; rt < 2; ++rt)
                #pragma unroll
                for (int i = 0; i < 4; ++i) {
                    int row = rt * 16 + (lane >> 4) * 4 + i;
                    thr[rt][i] = __int_as_float(rm_shared[row]) + MARGIN;
                }
        }
    }

    // ---- phase 5: exact refinement (bit-identical to round-2 keys) ----
    unsigned long long* best64 = (unsigned long long*)&scratchA[0][0];
    if (tid < RPB) best64[tid] = ~0ull;
    __syncthreads();
    int total = qn;
    if (total <= QCAP) {
        for (int t = tid; t < total; t += 256) {
            int e = queue[t];
            int row = e >> 10, code = e & 1023;
            const float4* cp = (const float4*)(cb + (size_t)code * D);
            const float*  zr = &z_lds[row][0];
            float acc = 0.0f;
            #pragma unroll 8
            for (int d4 = 0; d4 < 64; ++d4) {
                float4 cv = cp[d4];
                acc = fmaf(zr[d4 * 4 + 0], cv.x, acc);
                acc = fmaf(zr[d4 * 4 + 1], cv.y, acc);
                acc = fmaf(zr[d4 * 4 + 2], cv.z, acc);
                acc = fmaf(zr[d4 * 4 + 3], cv.w, acc);
            }
            float key = __fsub_rn(__fadd_rn(a_row[row], c2_lds[code]), 2.0f * acc);
            unsigned long long pk =
                ((unsigned long long)__float_as_uint(key) << 32) | (unsigned)code;
            atomicMin(&best64[row], pk);
        }
    } else {
        for (int r = 0; r < RPB; ++r) {
            for (int c = tid; c < NC; c += 256) {
                const float4* cp = (const float4*)(cb + (size_t)c * D);
                const float*  zr = &z_lds[r][0];
                float acc = 0.0f;
                #pragma unroll 8
                for (int d4 = 0; d4 < 64; ++d4) {
                    float4 cv = cp[d4];
                    acc = fmaf(zr[d4 * 4 + 0], cv.x, acc);
                    acc = fmaf(zr[d4 * 4 + 1], cv.y, acc);
                    acc = fmaf(zr[d4 * 4 + 2], cv.z, acc);
                    acc = fmaf(zr[d4 * 4 + 3], cv.w, acc);
                }
                float key = __fsub_rn(__fadd_rn(a_row[r], c2_lds[c]), 2.0f * acc);
                unsigned long long pk =
                    ((unsigned long long)__float_as_uint(key) << 32) | (unsigned)c;
                atomicMin(&best64[r], pk);
            }
        }
    }
    __syncthreads();

    // ---- phase 6: winners ----
    int* winner = rm_shared;   // reuse
    if (tid < RPB) {
        unsigned long long b = best64[tid];
        int wdx = (b == ~0ull) ? 0 : (int)(b & 0xffffffffu);
        winner[tid] = wdx;
        out_idx[rowBase + tid] = (float)wdx;
    }
    __syncthreads();

    // ---- phase 7: vectorized epilogue (float4 path, wave-uniform row) ----
    double lacc = 0.0;
    #pragma unroll
    for (int j = 0; j < 8; ++j) {
        int idx = tid + 256 * j;      // 0..2047
        int row = idx >> 6;           // wave-uniform
        int q4  = idx & 63;
        int wd  = winner[row];
        float4 cv = *(const float4*)(cb + (size_t)wd * D + q4 * 4);
        float4 zv = *(const float4*)&z_lds[row][q4 * 4];
        float4 o;
        o.x = __fadd_rn(zv.x, __fsub_rn(cv.x, zv.x));
        o.y = __fadd_rn(zv.y, __fsub_rn(cv.y, zv.y));
        o.z = __fadd_rn(zv.z, __fsub_rn(cv.z, zv.z));
        o.w = __fadd_rn(zv.w, __fsub_rn(cv.w, zv.w));
        *(float4*)(out_zq + (size_t)(rowBase + row) * D + q4 * 4) = o;
        double d0 = (double)zv.x - (double)cv.x;
        double d1 = (double)zv.y - (double)cv.y;
        double d2 = (double)zv.z - (double)cv.z;
        double d3 = (double)zv.w - (double)cv.w;
        lacc += d0 * d0 + d1 * d1 + d2 * d2 + d3 * d3;
    }
    __syncthreads();
    double* dred = (double*)&queue[0];   // 512 ints = 256 doubles
    dred[tid] = lacc;
    __syncthreads();
    for (int s = 128; s > 0; s >>= 1) {
        if (tid < s) dred[tid] += dred[tid + s];
        __syncthreads();
    }
    if (tid == 0) partials[blockIdx.x] = dred[0];
}

// --- final loss reduction ---------------------------------------------------
__global__ void loss_kernel(const double* __restrict__ partials,
                            float* __restrict__ out_loss)
{
    __shared__ double sm[256];
    int tid = threadIdx.x;
    double s = 0.0;
    for (int i = tid; i < NBLK; i += 256) s += partials[i];
    sm[tid] = s;
    __syncthreads();
    for (int k = 128; k > 0; k >>= 1) {
        if (tid < k) sm[tid] += sm[tid + k];
        __syncthreads();
    }
    if (tid == 0)
        out_loss[0] = (float)(1.25 * sm[0] / (double)((size_t)NROWS * D));
}

extern "C" void kernel_launch(void* const* d_in, const int* in_sizes, int n_in,
                              void* d_out, int out_size, void* d_ws, size_t ws_size,
                              hipStream_t stream)
{
    const float* z  = (const float*)d_in[0];   // [65536, 256]
    const float* cb = (const float*)d_in[1];   // [1024, 256]

    float* out      = (float*)d_out;
    float* out_zq   = out;
    float* out_loss = out + (size_t)NROWS * D;
    float* out_idx  = out_loss + 1;

    char*   ws       = (char*)d_ws;
    short*  cb_swz   = (short*)ws;                       // 512 KB
    float*  c2       = (float*)(ws + 524288);            // 4 KB
    double* partials = (double*)(ws + 528384);           // 16 KB

    swz_kernel<<<128, 256, 0, stream>>>(cb, cb_swz);
    c2_kernel<<<4, 256, 0, stream>>>(cb, c2);
    vq_kernel<<<NBLK, 256, 0, stream>>>(z, cb, cb_swz, c2,
                                        out_zq, out_idx, partials);
    loss_kernel<<<1, 256, 0, stream>>>(partials, out_loss);
}